// Round 5
// baseline (191.644 us; speedup 1.0000x reference)
//
#include <hip/hip_runtime.h>

// grid [2,160,160,160,3] fp32; interior 156^3 per batch.
#define OY 480
#define OX 76800
#define SB 12288000
#define JT 12                    // interior j rows per block (13 tiles)
#define KT 52                    // interior k per block (3 tiles)
#define IT 26                    // interior i marched per block (6 segs)
#define NBLK 468                 // 2 * 13 * 3 * 6
#define RWF 168                  // floats per staged row: 56 z-levels * 3
#define NROW 16                  // JT + 4 halo rows
#define SLICE (NROW*RWF)         // 2688 floats / slice buffer
#define NBUF 6                   // ring depth (single barrier/step safe)
#define NF4 (SLICE/4)            // 672 float4 per slice
#define NSTR 13                  // z-strips per row (L=4)
#define CTHR (JT*NSTR)           // 156 compute threads
#define INV_SIZE (1.0f/22778496.0f)

__device__ __forceinline__ void ld24(float* d, const float* s) {  // s 16B-aligned
    #pragma unroll
    for (int q = 0; q < 6; ++q)
        *(float4*)(d + 4*q) = *(const float4*)(s + 4*q);
}
__device__ __forceinline__ void ld12(float* d, const float* s) {  // s 8B-aligned
    *(float2*)(d)      = *(const float2*)(s);
    *(float4*)(d + 2)  = *(const float4*)(s + 2);
    *(float4*)(d + 6)  = *(const float4*)(s + 6);
    *(float2*)(d + 10) = *(const float2*)(s + 10);
}

// 256 threads. Marches i over IT slices with a 6-deep LDS slice ring.
// Staging: float4 global loads -> b128 LDS writes. Compute: 156 threads,
// each an L=4 z-strip -> wide (b128-dominant) LDS reads.
__global__ __launch_bounds__(256, 2)
void be_partials(const float* __restrict__ g, float* __restrict__ partial) {
    __shared__ float lds[NBUF * SLICE];
    __shared__ float wsum[4];

    const int tid = threadIdx.x;
    const int bid = blockIdx.x;
    const int is  = bid % 6;
    const int r1  = bid / 6;
    const int kt  = r1 % 3;
    const int r2  = r1 / 3;
    const int jt  = r2 % 13;
    const int bb  = r2 / 13;

    const int i_start = is * IT;       // global slice x base (window x=i..i+4)
    const int j0      = jt * JT;       // global row base (16 rows j0..j0+15)
    const int k0f     = kt * 156;      // global float offset of z-window start

    const float* __restrict__ G = g + (size_t)bb * SB;

    // ---- staging offsets: thread t -> float4 ids t, t+256, (t+512 if t<160)
    int gfl0, gfl1, gfl2 = 0, lfl0, lfl1, lfl2 = 0;
    {
        int f4, row, pos;
        f4 = tid;        row = f4 / 42; pos = f4 - row * 42;
        gfl0 = (j0 + row) * OY + k0f + 4 * pos;  lfl0 = row * RWF + 4 * pos;
        f4 = tid + 256;  row = f4 / 42; pos = f4 - row * 42;
        gfl1 = (j0 + row) * OY + k0f + 4 * pos;  lfl1 = row * RWF + 4 * pos;
    }
    const bool tail = tid < (NF4 - 512);      // 160 threads
    if (tail) {
        int f4 = tid + 512; int row = f4 / 42; int pos = f4 - row * 42;
        gfl2 = (j0 + row) * OY + k0f + 4 * pos;  lfl2 = row * RWF + 4 * pos;
    }

    // ---- compute mapping: strip of 4 z-points ----
    const bool act = tid < CTHR;
    int jj = tid / NSTR;
    int ss = tid - jj * NSTR;
    if (!act) { jj = 0; ss = 0; }
    const int rb = (jj + 2) * RWF + 12 * ss;   // strip row base (16B-aligned)

    // ---- warmup: stage slices x = i_start .. i_start+4 ----
    #pragma unroll
    for (int w = 0; w < 5; ++w) {
        const int gx = i_start + w;
        const float* base = G + (size_t)gx * OX;
        float4 v0 = *(const float4*)(base + gfl0);
        float4 v1 = *(const float4*)(base + gfl1);
        float4 v2 = tail ? *(const float4*)(base + gfl2) : make_float4(0,0,0,0);
        float* L = lds + (gx % NBUF) * SLICE;
        *(float4*)(L + lfl0) = v0;
        *(float4*)(L + lfl1) = v1;
        if (tail) *(float4*)(L + lfl2) = v2;
    }
    __syncthreads();

    float s = 0.0f;
    for (int i0 = 0; i0 < IT; ++i0) {
        const int gx = i_start + i0;

        // 1) issue next slice's global loads (consumed after compute)
        const bool doLoad = (i0 < IT - 1);
        float4 v0 = make_float4(0,0,0,0), v1 = v0, v2 = v0;
        if (doLoad) {
            const float* base = G + (size_t)(gx + 5) * OX;
            v0 = *(const float4*)(base + gfl0);
            v1 = *(const float4*)(base + gfl1);
            if (tail) v2 = *(const float4*)(base + gfl2);
        }

        // 2) compute from slices gx..gx+4
        if (act) {
            const float* S0 = lds + ((gx    ) % NBUF) * SLICE;  // x-2
            const float* S1 = lds + ((gx + 1) % NBUF) * SLICE;  // x-1
            const float* S2 = lds + ((gx + 2) % NBUF) * SLICE;  // center
            const float* S3 = lds + ((gx + 3) % NBUF) * SLICE;  // x+1
            const float* S4 = lds + ((gx + 4) % NBUF) * SLICE;  // x+2

            float w1a = 0.f, w2a = 0.f, w3a = 0.f, w4a = 0.f;

            // center row j (24 fl): hzz + center values
            float C[24]; ld24(C, S2 + rb);

            // j+-2 rows: hyy (c0,c1)
            {
                float U[12], D[12];
                ld12(U, S2 + rb + 2*RWF + 6);
                ld12(D, S2 + rb - 2*RWF + 6);
                #pragma unroll
                for (int p = 0; p < 4; ++p) {
                    float hyy0 = U[3*p]   - 2.0f*C[6+3*p]   + D[3*p];
                    float hyy1 = U[3*p+1] - 2.0f*C[6+3*p+1] + D[3*p+1];
                    w2a = fmaf(hyy0, hyy0, w2a);
                    w1a = fmaf(hyy1, hyy1, w1a);
                }
            }
            // j+-1 rows: hyz (3 comps); plus hzz from C
            {
                float A[24], Bv[24];
                ld24(A,  S2 + rb + RWF);
                ld24(Bv, S2 + rb - RWF);
                #pragma unroll
                for (int p = 0; p < 4; ++p) {
                    const int o = 3 * p;
                    float hzz0 = C[12+o]   - 2.0f*C[6+o]   + C[o];
                    float hzz1 = C[12+o+1] - 2.0f*C[6+o+1] + C[o+1];
                    float hzz2 = C[12+o+2] - 2.0f*C[6+o+2] + C[o+2];
                    w2a = fmaf(hzz0, hzz0, w2a);
                    w2a = fmaf(hzz1, hzz1, w2a);
                    w1a = fmaf(hzz2, hzz2, w1a);
                    float hyz0 = (A[9+o]   - A[3+o])   - (Bv[9+o]   - Bv[3+o]);
                    float hyz1 = (A[9+o+1] - A[3+o+1]) - (Bv[9+o+1] - Bv[3+o+1]);
                    float hyz2 = (A[9+o+2] - A[3+o+2]) - (Bv[9+o+2] - Bv[3+o+2]);
                    w4a = fmaf(hyz0, hyz0, w4a);
                    w3a = fmaf(hyz1, hyz1, w3a);
                    w1a = fmaf(hyz2, hyz2, w1a);
                }
            }
            // x+-1 row j: hxz (3 comps)
            {
                float P[24], M[24];
                ld24(P, S3 + rb);
                ld24(M, S1 + rb);
                #pragma unroll
                for (int p = 0; p < 4; ++p) {
                    const int o = 3 * p;
                    float hxz0 = (P[9+o]   - P[3+o])   - (M[9+o]   - M[3+o]);
                    float hxz1 = (P[9+o+1] - P[3+o+1]) - (M[9+o+1] - M[3+o+1]);
                    float hxz2 = (P[9+o+2] - P[3+o+2]) - (M[9+o+2] - M[3+o+2]);
                    w3a = fmaf(hxz0, hxz0, w3a);
                    w2a = fmaf(hxz1, hxz1, w2a);
                    w1a = fmaf(hxz2, hxz2, w1a);
                }
            }
            // x+-1, j+-1: hxy (c0,c1)
            {
                float PU[12], PD[12], MU[12], MD[12];
                ld12(PU, S3 + rb + RWF + 6);
                ld12(PD, S3 + rb - RWF + 6);
                ld12(MU, S1 + rb + RWF + 6);
                ld12(MD, S1 + rb - RWF + 6);
                #pragma unroll
                for (int p = 0; p < 4; ++p) {
                    float hxy0 = (PU[3*p]   - PD[3*p])   - (MU[3*p]   - MD[3*p]);
                    float hxy1 = (PU[3*p+1] - PD[3*p+1]) - (MU[3*p+1] - MD[3*p+1]);
                    w3a = fmaf(hxy0, hxy0, w3a);
                    w1a = fmaf(hxy1, hxy1, w1a);
                }
            }
            // x+-2 row j: hxx (c0)
            #pragma unroll
            for (int p = 0; p < 4; ++p) {
                float hxx0 = S4[rb + 6 + 3*p] - 2.0f*C[6+3*p] + S0[rb + 6 + 3*p];
                w1a = fmaf(hxx0, hxx0, w1a);
            }

            float t = fmaf(2.0f, w2a, w1a);
            t = fmaf(3.0f, w3a, t);
            t = fmaf(4.0f, w4a, t);
            s = fmaf(0.0625f, t, s);
        }

        // 3) retire staged slice (buffer (gx+5)%6 not read this step)
        if (doLoad) {
            float* L = lds + ((gx + 5) % NBUF) * SLICE;
            *(float4*)(L + lfl0) = v0;
            *(float4*)(L + lfl1) = v1;
            if (tail) *(float4*)(L + lfl2) = v2;
        }
        __syncthreads();
    }

    // ---- block reduction ----
    #pragma unroll
    for (int off = 32; off > 0; off >>= 1) s += __shfl_down(s, off, 64);
    if ((tid & 63) == 0) wsum[tid >> 6] = s;
    __syncthreads();
    if (tid == 0)
        partial[bid] = (wsum[0] + wsum[1]) + (wsum[2] + wsum[3]);
}

__global__ __launch_bounds__(256)
void be_final(const float* __restrict__ partial, float* __restrict__ out) {
    float s = 0.0f;
    for (int i = threadIdx.x; i < NBLK; i += 256) s += partial[i];
    #pragma unroll
    for (int off = 32; off > 0; off >>= 1) s += __shfl_down(s, off, 64);
    __shared__ float ws[4];
    if ((threadIdx.x & 63) == 0) ws[threadIdx.x >> 6] = s;
    __syncthreads();
    if (threadIdx.x == 0)
        out[0] = ((ws[0] + ws[1]) + (ws[2] + ws[3])) * INV_SIZE;
}

extern "C" void kernel_launch(void* const* d_in, const int* in_sizes, int n_in,
                              void* d_out, int out_size, void* d_ws, size_t ws_size,
                              hipStream_t stream) {
    const float* grid = (const float*)d_in[0];
    float* out = (float*)d_out;
    float* partials = (float*)d_ws;    // 468 floats

    be_partials<<<dim3(NBLK), dim3(256), 0, stream>>>(grid, partials);
    be_final<<<1, 256, 0, stream>>>(partials, out);
}

// Round 6
// 172.263 us; speedup vs baseline: 1.1125x; 1.1125x over previous
//
#include <hip/hip_runtime.h>

// grid [2,160,160,160,3] fp32; interior 156^3 per batch.
#define OY 480
#define OX 76800
#define SB 12288000
#define SUBW 60                  // padded subrow stride (56 z staged)
#define ROWW 180                 // 3 subrows (SoA per row: c0|c1|c2)
#define SLICE 3060               // 17 rows * ROWW
#define NBUF 6                   // slice ring (single barrier/step safe)
#define NCHUNK 714               // 17 rows * 42 float4 staged per slice
#define NBLK 504                 // 2 batch * 12 jt * 3 kt * 7 iseg
#define INV_SIZE (1.0f/22778496.0f)

#define LD8(dst, p)  { *(float4*)(dst) = *(const float4*)(p); \
                       *(float4*)((dst)+4) = *(const float4*)((p)+4); }
#define LD4Z(dst, p) { *(float2*)(dst) = *(const float2*)((p)+2); \
                       *(float2*)((dst)+2) = *(const float2*)((p)+4); }

// 256 threads; tile = 13 j-rows x 52 z, marching ~22 i-slices through a
// 6-deep LDS slice ring. LDS layout is SoA-per-row so compute threads
// (169, each a 4-z strip) read aligned b128/b64. Staging transposes
// AoS global float4 -> 4 precomputed-address b32 LDS writes.
__global__ __launch_bounds__(256, 2)
void be_partials(const float* __restrict__ g, float* __restrict__ partial) {
    __shared__ float lds[NBUF * SLICE];
    __shared__ float wsum[4];

    const int tid  = threadIdx.x;
    const int bid  = blockIdx.x;
    const int iseg = bid % 7;
    int r = bid / 7;
    const int kt = r % 3; r /= 3;
    const int jt = r % 12;
    const int bb = r / 12;
    const int j0  = jt * 13;                 // staged rows j_g in [j0, j0+16]
    const int kf0 = kt * 156;                // z-window start (float offset, %4==0)
    const int i0  = (iseg < 2) ? 23 * iseg : 46 + 22 * (iseg - 2);
    const int len = (iseg < 2) ? 23 : 22;    // interior i per segment

    const float* __restrict__ G = g + (size_t)bb * SB;

    // ---- staging precompute (addresses fixed across all slices) ----
    int goff[3], loff[3][4];
    bool have2;
    #pragma unroll
    for (int c = 0; c < 3; ++c) {
        const int cid = tid + 256 * c;
        const int row = cid / 42, q = cid - row * 42;
        goff[c] = (j0 + row) * OY + kf0 + 4 * q;
        #pragma unroll
        for (int m = 0; m < 4; ++m) {
            const int gf = 4 * q + m;
            const int zl = gf / 3;
            const int cc = gf - 3 * zl;
            loff[c][m] = row * ROWW + cc * SUBW + zl;
        }
    }
    have2 = tid < (NCHUNK - 512);            // 202 threads carry a 3rd chunk

    // ---- compute mapping: 169 strips (13 rows x 13 z-strips of 4) ----
    const bool act = tid < 169;
    const int jj = act ? tid / 13 : 0;
    const int ss = act ? (tid - jj * 13) : 0;
    const int rb = (jj + 2) * ROWW;          // LDS row of interior j
    const int wb = 4 * ss;                   // z-window base (points at wb+2..wb+5)

    // ---- warmup: stage slices x = i0 .. i0+4 ----
    for (int w = 0; w < 5; ++w) {
        const float* base = G + (size_t)(i0 + w) * OX;
        float* L = lds + ((i0 + w) % NBUF) * SLICE;
        #pragma unroll
        for (int c = 0; c < 3; ++c) {
            if (c < 2 || have2) {
                float4 v = *(const float4*)(base + goff[c]);
                L[loff[c][0]] = v.x; L[loff[c][1]] = v.y;
                L[loff[c][2]] = v.z; L[loff[c][3]] = v.w;
            }
        }
    }
    __syncthreads();

    float w1 = 0.f, w2 = 0.f, w3 = 0.f, w4 = 0.f;
    for (int t = 0; t < len; ++t) {
        const int cg = i0 + 2 + t;           // absolute center slice
        const bool doLoad = t < len - 1;
        float4 v0 = make_float4(0,0,0,0), v1 = v0, v2 = v0;
        if (doLoad) {                        // prefetch x = cg+3
            const float* base = G + (size_t)(cg + 3) * OX;
            v0 = *(const float4*)(base + goff[0]);
            v1 = *(const float4*)(base + goff[1]);
            if (have2) v2 = *(const float4*)(base + goff[2]);
        }

        if (act) {
            const float* S0 = lds + ((cg - 2) % NBUF) * SLICE;
            const float* S1 = lds + ((cg - 1) % NBUF) * SLICE;
            const float* S2 = lds + ((cg    ) % NBUF) * SLICE;
            const float* S3 = lds + ((cg + 1) % NBUF) * SLICE;
            const float* S4 = lds + ((cg + 2) % NBUF) * SLICE;

            // center row, 3 comps (A kept for hyy/hxx centers)
            float A[8], Bv[8], Cv[8];
            const float* cr = S2 + rb + wb;
            LD8(A,  cr); LD8(Bv, cr + SUBW); LD8(Cv, cr + 2*SUBW);
            #pragma unroll
            for (int q = 0; q < 4; ++q) {
                float hzz0 = A[4+q]  - 2.f*A[2+q]  + A[q];
                float hzz1 = Bv[4+q] - 2.f*Bv[2+q] + Bv[q];
                float hzz2 = Cv[4+q] - 2.f*Cv[2+q] + Cv[q];
                w2 = fmaf(hzz0, hzz0, w2);
                w2 = fmaf(hzz1, hzz1, w2);
                w1 = fmaf(hzz2, hzz2, w1);
            }
            // hyz: rows j+-1, 3 comps (z+-1 within window)
            {
                const float* up = S2 + rb + ROWW + wb;
                const float* dn = S2 + rb - ROWW + wb;
                float P[8], M[8];
                LD8(P, up); LD8(M, dn);
                #pragma unroll
                for (int q = 0; q < 4; ++q) {
                    float h = (P[3+q] - P[1+q]) - (M[3+q] - M[1+q]);
                    w4 = fmaf(h, h, w4);
                }
                LD8(P, up + SUBW); LD8(M, dn + SUBW);
                #pragma unroll
                for (int q = 0; q < 4; ++q) {
                    float h = (P[3+q] - P[1+q]) - (M[3+q] - M[1+q]);
                    w3 = fmaf(h, h, w3);
                }
                LD8(P, up + 2*SUBW); LD8(M, dn + 2*SUBW);
                #pragma unroll
                for (int q = 0; q < 4; ++q) {
                    float h = (P[3+q] - P[1+q]) - (M[3+q] - M[1+q]);
                    w1 = fmaf(h, h, w1);
                }
            }
            // hyy: rows j+-2, comps 0,1 (exact z)
            {
                const float* up = S2 + rb + 2*ROWW + wb;
                const float* dn = S2 + rb - 2*ROWW + wb;
                float P0[4], M0[4], P1[4], M1[4];
                LD4Z(P0, up); LD4Z(M0, dn);
                LD4Z(P1, up + SUBW); LD4Z(M1, dn + SUBW);
                #pragma unroll
                for (int q = 0; q < 4; ++q) {
                    float h0 = P0[q] - 2.f*A[2+q]  + M0[q];
                    float h1 = P1[q] - 2.f*Bv[2+q] + M1[q];
                    w2 = fmaf(h0, h0, w2);
                    w1 = fmaf(h1, h1, w1);
                }
            }
            // hxz: slices x+-1, row j, 3 comps (z+-1)
            {
                const float* pp = S3 + rb + wb;
                const float* mm = S1 + rb + wb;
                float P[8], M[8];
                LD8(P, pp); LD8(M, mm);
                #pragma unroll
                for (int q = 0; q < 4; ++q) {
                    float h = (P[3+q] - P[1+q]) - (M[3+q] - M[1+q]);
                    w3 = fmaf(h, h, w3);
                }
                LD8(P, pp + SUBW); LD8(M, mm + SUBW);
                #pragma unroll
                for (int q = 0; q < 4; ++q) {
                    float h = (P[3+q] - P[1+q]) - (M[3+q] - M[1+q]);
                    w2 = fmaf(h, h, w2);
                }
                LD8(P, pp + 2*SUBW); LD8(M, mm + 2*SUBW);
                #pragma unroll
                for (int q = 0; q < 4; ++q) {
                    float h = (P[3+q] - P[1+q]) - (M[3+q] - M[1+q]);
                    w1 = fmaf(h, h, w1);
                }
            }
            // hxy: slices x+-1, rows j+-1, comps 0,1 (exact z)
            {
                const float* pu = S3 + rb + ROWW + wb;
                const float* pd = S3 + rb - ROWW + wb;
                const float* mu = S1 + rb + ROWW + wb;
                const float* md = S1 + rb - ROWW + wb;
                float a[4], b[4], c[4], d[4];
                LD4Z(a, pu); LD4Z(b, pd); LD4Z(c, mu); LD4Z(d, md);
                #pragma unroll
                for (int q = 0; q < 4; ++q) {
                    float h = (a[q] - b[q]) - (c[q] - d[q]);
                    w3 = fmaf(h, h, w3);
                }
                LD4Z(a, pu + SUBW); LD4Z(b, pd + SUBW);
                LD4Z(c, mu + SUBW); LD4Z(d, md + SUBW);
                #pragma unroll
                for (int q = 0; q < 4; ++q) {
                    float h = (a[q] - b[q]) - (c[q] - d[q]);
                    w1 = fmaf(h, h, w1);
                }
            }
            // hxx: slices x+-2, row j, comp 0 (exact z)
            {
                float p[4], m[4];
                LD4Z(p, S4 + rb + wb); LD4Z(m, S0 + rb + wb);
                #pragma unroll
                for (int q = 0; q < 4; ++q) {
                    float h = p[q] - 2.f*A[2+q] + m[q];
                    w1 = fmaf(h, h, w1);
                }
            }
        }

        if (doLoad) {                        // retire prefetch to slot (cg+3)%6
            float* L = lds + ((cg + 3) % NBUF) * SLICE;
            L[loff[0][0]] = v0.x; L[loff[0][1]] = v0.y;
            L[loff[0][2]] = v0.z; L[loff[0][3]] = v0.w;
            L[loff[1][0]] = v1.x; L[loff[1][1]] = v1.y;
            L[loff[1][2]] = v1.z; L[loff[1][3]] = v1.w;
            if (have2) {
                L[loff[2][0]] = v2.x; L[loff[2][1]] = v2.y;
                L[loff[2][2]] = v2.z; L[loff[2][3]] = v2.w;
            }
        }
        __syncthreads();
    }

    float s = fmaf(2.f, w2, w1);
    s = fmaf(3.f, w3, s);
    s = fmaf(4.f, w4, s);
    s *= 0.0625f;

    #pragma unroll
    for (int off = 32; off > 0; off >>= 1) s += __shfl_down(s, off, 64);
    if ((tid & 63) == 0) wsum[tid >> 6] = s;
    __syncthreads();
    if (tid == 0)
        partial[bid] = (wsum[0] + wsum[1]) + (wsum[2] + wsum[3]);
}

__global__ __launch_bounds__(256)
void be_final(const float* __restrict__ partial, float* __restrict__ out) {
    float s = 0.0f;
    for (int i = threadIdx.x; i < NBLK; i += 256) s += partial[i];
    #pragma unroll
    for (int off = 32; off > 0; off >>= 1) s += __shfl_down(s, off, 64);
    __shared__ float ws[4];
    if ((threadIdx.x & 63) == 0) ws[threadIdx.x >> 6] = s;
    __syncthreads();
    if (threadIdx.x == 0)
        out[0] = ((ws[0] + ws[1]) + (ws[2] + ws[3])) * INV_SIZE;
}

extern "C" void kernel_launch(void* const* d_in, const int* in_sizes, int n_in,
                              void* d_out, int out_size, void* d_ws, size_t ws_size,
                              hipStream_t stream) {
    const float* grid = (const float*)d_in[0];
    float* out = (float*)d_out;
    float* partials = (float*)d_ws;          // 504 floats

    be_partials<<<dim3(NBLK), dim3(256), 0, stream>>>(grid, partials);
    be_final<<<1, 256, 0, stream>>>(partials, out);
}